// Round 3
// baseline (3005.429 us; speedup 1.0000x reference)
//
#include <hip/hip_runtime.h>
#include <hip/hip_bf16.h>
#include <cstdint>
#include <cstddef>

#define NN 20000
#define NE 200000
#define NG 128
#define HID 256

typedef __bf16 bfrag8 __attribute__((ext_vector_type(8)));  // 8 bf16 (4 VGPRs)
typedef float  accf4  __attribute__((ext_vector_type(4)));  // 4 fp32 acc

__device__ __forceinline__ unsigned short f2bf(float f) {
    union { float f; unsigned int i; } x; x.f = f;
    unsigned int r = x.i + 0x7fffu + ((x.i >> 16) & 1u);  // RNE
    return (unsigned short)(r >> 16);
}
__device__ __forceinline__ __bf16 f2bf16t(float f) {
    union { unsigned short u; __bf16 b; } x; x.u = f2bf(f); return x.b;
}
__device__ __forceinline__ float sspf(float x) {
    // softplus(x) - log(2), numerically stable
    return fmaxf(x, 0.f) + log1pf(expf(-fabsf(x))) - 0.69314718055994530942f;
}

// A-operand spec: virtual A[M, nblocks*256] = concat of up to 4 [.,256] sources,
// each with optional row-index indirection (nullptr => identity) and a per-block
// dtype flag (f32mask bit b set => base[b] is const float*, else bf16).
struct ASpec {
    const void* base[4];
    const int* idx[4];
    int f32mask;
    int nblocks;
};

// out[M,256] = ssp( A_virtual[M,K] @ Wbf16[256,K]^T ) (+ resid_f32), out f32 or bf16.
// Block: 4 waves x 16 rows = 64 rows, each wave covers all 256 out-cols.
// In-place safe when out aliases an identity-indexed A block: each wave reads only
// its own 16 rows in the k-loop, all reads complete before epilogue stores, and
// clamped tail rows never produce stores (r < M guard).
__global__ __launch_bounds__(256) void gemm_ssp_kernel(
    ASpec A, const unsigned short* __restrict__ W,
    void* __restrict__ out, int out_f32,
    const float* __restrict__ resid, int M)
{
    const int K    = A.nblocks * HID;
    const int lane = threadIdx.x & 63;
    const int wave = threadIdx.x >> 6;
    const int l15  = lane & 15;      // A row-in-tile on load; D col on store
    const int kg   = lane >> 4;      // k-group 0..3
    const int rowbase = blockIdx.x * 64 + wave * 16;
    const int m  = rowbase + l15;
    const int mc = m < M ? m : (M - 1);

    int ridx[4];
    #pragma unroll
    for (int b = 0; b < 4; b++) {
        ridx[b] = 0;
        if (b < A.nblocks) ridx[b] = A.idx[b] ? A.idx[b][mc] : mc;
    }

    accf4 acc[16];
    #pragma unroll
    for (int i = 0; i < 16; i++) acc[i] = (accf4){0.f, 0.f, 0.f, 0.f};

    const int ksteps = A.nblocks * (HID / 32);
    for (int kt = 0; kt < ksteps; kt++) {
        const int b   = kt >> 3;                       // which 256-block
        const int kin = ((kt & 7) * 32) + kg * 8;      // offset within source row
        bfrag8 afrag;
        if ((A.f32mask >> b) & 1) {
            const float* ap = (const float*)A.base[b] + (size_t)ridx[b] * HID + kin;
            const float4* ap4 = (const float4*)ap;
            float4 x = ap4[0], y = ap4[1];
            afrag[0] = f2bf16t(x.x); afrag[1] = f2bf16t(x.y);
            afrag[2] = f2bf16t(x.z); afrag[3] = f2bf16t(x.w);
            afrag[4] = f2bf16t(y.x); afrag[5] = f2bf16t(y.y);
            afrag[6] = f2bf16t(y.z); afrag[7] = f2bf16t(y.w);
        } else {
            const unsigned short* ap = (const unsigned short*)A.base[b] + (size_t)ridx[b] * HID + kin;
            afrag = *(const bfrag8*)ap;
        }
        const int kglob = kt * 32 + kg * 8;
        #pragma unroll
        for (int ct = 0; ct < 16; ct++) {
            const unsigned short* wp = W + (size_t)(ct * 16 + l15) * K + kglob;
            bfrag8 bfrag = *(const bfrag8*)wp;
            acc[ct] = __builtin_amdgcn_mfma_f32_16x16x32_bf16(afrag, bfrag, acc[ct], 0, 0, 0);
        }
    }

    const int r0 = rowbase + kg * 4;   // D rows for this lane
    #pragma unroll
    for (int ct = 0; ct < 16; ct++) {
        #pragma unroll
        for (int rg = 0; rg < 4; rg++) {
            int r = r0 + rg;
            if (r < M) {
                int c = ct * 16 + l15;
                size_t off = (size_t)r * HID + c;
                float v = sspf(acc[ct][rg]);
                if (resid) v += resid[off];
                if (out_f32) ((float*)out)[off] = v;
                else ((unsigned short*)out)[off] = f2bf(v);
            }
        }
    }
}

__global__ void cvt_w_kernel(const float* __restrict__ src, unsigned short* __restrict__ dst, int n) {
    int i = blockIdx.x * 256 + threadIdx.x;
    if (i < n) dst[i] = f2bf(src[i]);
}

__global__ void zero_f32_kernel(float* __restrict__ p, int n) {
    int i = blockIdx.x * 256 + threadIdx.x;
    if (i < n) p[i] = 0.f;
}

__global__ void be_counts_kernel(const int* __restrict__ src, const int* __restrict__ dst,
                                 const int* __restrict__ batch, int* __restrict__ be,
                                 float* __restrict__ cnt_n, float* __restrict__ cnt_eg) {
    int e = blockIdx.x * 256 + threadIdx.x;
    if (e < NE) {
        int b = batch[src[e]];
        be[e] = b;
        atomicAdd(&cnt_n[dst[e]], 1.f);
        atomicAdd(&cnt_eg[b], 1.f);
    }
}

__global__ void node_counts_kernel(const int* __restrict__ batch, float* __restrict__ cnt_ng) {
    int i = blockIdx.x * 256 + threadIdx.x;
    if (i < NN) atomicAdd(&cnt_ng[batch[i]], 1.f);
}

// one block per edge row (256 threads = 256 cols); e_mid is f32
__global__ void scatter_edges_kernel(const float* __restrict__ emid,
                                     const int* __restrict__ dst, const int* __restrict__ be,
                                     float* __restrict__ e2n_sum, float* __restrict__ e2g_sum) {
    int e = blockIdx.x;
    int c = threadIdx.x;
    float v = emid[(size_t)e * HID + c];
    atomicAdd(&e2n_sum[(size_t)dst[e] * HID + c], v);
    atomicAdd(&e2g_sum[(size_t)be[e] * HID + c], v);
}

// n_mid is bf16
__global__ void scatter_nodes_kernel(const unsigned short* __restrict__ nmid,
                                     const int* __restrict__ batch, float* __restrict__ n2g_sum) {
    int i = blockIdx.x;
    int c = threadIdx.x;
    union { unsigned int u; float f; } x; x.u = ((unsigned int)nmid[(size_t)i * HID + c]) << 16;
    atomicAdd(&n2g_sum[(size_t)batch[i] * HID + c], x.f);
}

__global__ void mean_kernel(const float* __restrict__ sum, const float* __restrict__ cnt,
                            unsigned short* __restrict__ out, int M) {
    int gid = blockIdx.x * 256 + threadIdx.x;
    if (gid < M * HID) {
        int r = gid >> 8;
        out[gid] = f2bf(sum[gid] / fmaxf(cnt[r], 1.f));
    }
}

extern "C" void kernel_launch(void* const* d_in, const int* in_sizes, int n_in,
                              void* d_out, int out_size, void* d_ws, size_t ws_size,
                              hipStream_t stream)
{
    (void)in_sizes; (void)n_in; (void)out_size; (void)ws_size;
    const float* node_feats = (const float*)d_in[0];
    const float* edge_feats = (const float*)d_in[1];
    const float* glob_feats = (const float*)d_in[2];
    const int* edge_index   = (const int*)d_in[3];
    const int* batch        = (const int*)d_in[4];
    const float* Wf[9] = {
        (const float*)d_in[5],  (const float*)d_in[6],  (const float*)d_in[7],
        (const float*)d_in[8],  (const float*)d_in[9],  (const float*)d_in[10],
        (const float*)d_in[11], (const float*)d_in[12], (const float*)d_in[13],
    };
    const int Wn[9] = { HID*HID, HID*HID, HID*HID,
                        HID*4*HID, HID*3*HID, HID*3*HID,
                        HID*HID, HID*HID, HID*HID };

    const int* src = edge_index;        // edge_index[0]
    const int* dst = edge_index + NE;   // edge_index[1]

    float* out_n = (float*)d_out;                       // [NN,256] f32
    float* out_e = out_n + (size_t)NN * HID;            // [NE,256] f32
    float* out_g = out_e + (size_t)NE * HID;            // [NG,256] f32

    // ws layout (~34 MB). Zero-init region first -> single memsetAsync.
    char* ws = (char*)d_ws;
    size_t off = 0;
    auto alloc = [&](size_t bytes) -> char* {
        char* p = ws + off; off += (bytes + 255) & ~(size_t)255; return p;
    };
    float* e2g_sum = (float*)alloc((size_t)NG * HID * 4);
    float* n2g_sum = (float*)alloc((size_t)NG * HID * 4);
    float* cnt_n   = (float*)alloc((size_t)NN * 4);
    float* cnt_eg  = (float*)alloc((size_t)NG * 4);
    float* cnt_ng  = (float*)alloc((size_t)NG * 4);
    size_t zero_bytes = off;
    hipMemsetAsync(d_ws, 0, zero_bytes, stream);

    int* be                  = (int*)alloc((size_t)NE * 4);
    unsigned short* n1       = (unsigned short*)alloc((size_t)NN * HID * 2);
    unsigned short* g1       = (unsigned short*)alloc((size_t)NG * HID * 2);
    unsigned short* e2n_mean = (unsigned short*)alloc((size_t)NN * HID * 2);
    unsigned short* n_mid    = (unsigned short*)alloc((size_t)NN * HID * 2);
    unsigned short* n2g_mean = (unsigned short*)alloc((size_t)NG * HID * 2);
    unsigned short* e2g_mean = (unsigned short*)alloc((size_t)NG * HID * 2);
    unsigned short* g_mid    = (unsigned short*)alloc((size_t)NG * HID * 2);
    unsigned short* Wb[9];
    for (int i = 0; i < 9; i++) Wb[i] = (unsigned short*)alloc((size_t)Wn[i] * 2);

    // Aliases into d_out:
    float* e1      = out_e;   // stage-1 edge activations, f32, in place
    float* e_mid   = out_e;   // edge-MLP output, f32, in place (identity rows)
    float* e2n_sum = out_n;   // f32 atomic target; dead before final node GEMM writes out_n

    // weights -> bf16 (9 tiny launches, 1M elements total)
    for (int i = 0; i < 9; i++)
        cvt_w_kernel<<<(Wn[i] + 255) / 256, 256, 0, stream>>>(Wf[i], Wb[i], Wn[i]);

    zero_f32_kernel<<<(NN * HID + 255) / 256, 256, 0, stream>>>(e2n_sum, NN * HID);
    be_counts_kernel<<<(NE + 255) / 256, 256, 0, stream>>>(src, dst, batch, be, cnt_n, cnt_eg);
    node_counts_kernel<<<(NN + 255) / 256, 256, 0, stream>>>(batch, cnt_ng);

    auto launch_gemm = [&](const ASpec& A, const unsigned short* W, void* o, int of32,
                           const float* resid, int M) {
        gemm_ssp_kernel<<<(M + 63) / 64, 256, 0, stream>>>(A, W, o, of32, resid, M);
    };

    // stage 1: lin_*_1 + ssp
    { ASpec a{}; a.base[0] = node_feats; a.f32mask = 1; a.nblocks = 1;
      launch_gemm(a, Wb[0], n1, 0, nullptr, NN); }
    { ASpec a{}; a.base[0] = edge_feats; a.f32mask = 1; a.nblocks = 1;
      launch_gemm(a, Wb[1], e1, 1, nullptr, NE); }
    { ASpec a{}; a.base[0] = glob_feats; a.f32mask = 1; a.nblocks = 1;
      launch_gemm(a, Wb[2], g1, 0, nullptr, NG); }

    // EdgeModel: gather-concat fused into A-load, K=1024 (in place on out_e)
    { ASpec a{};
      a.base[0] = n1; a.idx[0] = src;
      a.base[1] = n1; a.idx[1] = dst;
      a.base[2] = e1; a.idx[2] = nullptr;
      a.base[3] = g1; a.idx[3] = be;
      a.f32mask = 0b0100;   // block 2 (e1) is f32
      a.nblocks = 4;
      launch_gemm(a, Wb[3], e_mid, 1, nullptr, NE); }

    // scatter-mean edges -> nodes (sum in out_n region) and edges -> graphs
    scatter_edges_kernel<<<NE, 256, 0, stream>>>(e_mid, dst, be, e2n_sum, e2g_sum);
    mean_kernel<<<(NN * HID + 255) / 256, 256, 0, stream>>>(e2n_sum, cnt_n, e2n_mean, NN);

    // NodeModel: K=768 -> n_mid bf16
    { ASpec a{};
      a.base[0] = n1; a.base[1] = e2n_mean;
      a.base[2] = g1; a.idx[2] = batch;
      a.f32mask = 0; a.nblocks = 3;
      launch_gemm(a, Wb[4], n_mid, 0, nullptr, NN); }

    // scatter-mean nodes -> graphs
    scatter_nodes_kernel<<<NN, 256, 0, stream>>>(n_mid, batch, n2g_sum);
    mean_kernel<<<(NG * HID + 255) / 256, 256, 0, stream>>>(n2g_sum, cnt_ng, n2g_mean, NG);
    mean_kernel<<<(NG * HID + 255) / 256, 256, 0, stream>>>(e2g_sum, cnt_eg, e2g_mean, NG);

    // GlobalModel: K=768 -> g_mid bf16
    { ASpec a{};
      a.base[0] = n2g_mean; a.base[1] = e2g_mean; a.base[2] = g1;
      a.f32mask = 0; a.nblocks = 3;
      launch_gemm(a, Wb[5], g_mid, 0, nullptr, NG); }

    // final lin_*_2 + ssp + residual -> f32 d_out (edge runs in place on out_e)
    { ASpec a{}; a.base[0] = n_mid; a.f32mask = 0; a.nblocks = 1;
      launch_gemm(a, Wb[6], out_n, 1, node_feats, NN); }
    { ASpec a{}; a.base[0] = e_mid; a.f32mask = 1; a.nblocks = 1;
      launch_gemm(a, Wb[7], out_e, 1, edge_feats, NE); }
    { ASpec a{}; a.base[0] = g_mid; a.f32mask = 0; a.nblocks = 1;
      launch_gemm(a, Wb[8], out_g, 1, glob_feats, NG); }
}